// Round 15
// baseline (665.832 us; speedup 1.0000x reference)
//
#include <hip/hip_runtime.h>
#include <cmath>

// Problem constants
constexpr int Bb  = 8;
constexpr int Tt  = 2048;
constexpr int DIN = 512;
constexpr int Dd  = 1024;
constexpr long long BT  = (long long)Bb * Tt;   // 16384
constexpr long long BTD = BT * Dd;              // 16777216

// ===== FROZEN NUMERICS (verified PASS rounds 9-14, absmax 0.03125) =========
__device__ __forceinline__ float np_expf(float x) {
  const float LOG2E = 1.4426950408889634074f;
  const float MAGIC = 12582912.0f;              // 0x1.8p23
  const float C1 = -6.93145752e-1f;
  const float C2 = -1.42860677e-6f;
  const float P0 = 9.999999999980870924916e-01f;
  const float P1 = 7.257664613233124478488e-01f;
  const float P2 = 2.473615434895520810817e-01f;
  const float P3 = 5.114512081637298353406e-02f;
  const float P4 = 6.757896990527504603057e-03f;
  const float P5 = 5.082762527590693718096e-04f;
  const float Q0 = 1.0f;
  const float Q1 = -2.742335390411667452936e-01f;
  const float Q2 = 2.159509375685829852307e-02f;
  const float XMAX = 88.72283935546875f;
  const float XMIN = -87.3365478515625f;
  if (!(x == x)) return x;
  if (x > XMAX)  return __builtin_inff();
  if (x < XMIN)  return 0.0f;
  float q = __fsub_rn(fmaf(x, LOG2E, MAGIC), MAGIC);
  float r = fmaf(q, C1, x);
  r = fmaf(q, C2, r);
  float num = fmaf(r, P5, P4);
  num = fmaf(num, r, P3);
  num = fmaf(num, r, P2);
  num = fmaf(num, r, P1);
  num = fmaf(num, r, P0);
  float den = fmaf(r, Q2, Q1);
  den = fmaf(den, r, Q0);
  float p = __fdiv_rn(num, den);
  return ldexpf(p, (int)q);
}

__device__ __forceinline__ float expf_cr(float x) { return (float)exp((double)x); }

__device__ __forceinline__ float log1pf_fd(float x) {
  const float ln2_hi = __int_as_float(0x3f317180);
  const float ln2_lo = __int_as_float(0x3717f7d1);
  const float Lp1 = __int_as_float(0x3F2AAAAB), Lp2 = __int_as_float(0x3ECCCCCD),
              Lp3 = __int_as_float(0x3E924925), Lp4 = __int_as_float(0x3E638E29),
              Lp5 = __int_as_float(0x3E3A3325), Lp6 = __int_as_float(0x3E1CD04F),
              Lp7 = __int_as_float(0x3E178897);
  int hx = __float_as_int(x);
  int ax = hx & 0x7fffffff;
  int k = 1, hu = 0;
  float f = 0.f, c = 0.f, u;
  if (hx < 0x3ed413d7) {
    if (ax < 0x38000000) {
      if (ax < 0x33800000) return x;
      return __fsub_rn(x, __fmul_rn(__fmul_rn(x, x), 0.5f));
    }
    if (hx > 0 || hx <= (int)0xbe95f61f) { k = 0; f = x; hu = 1; }
  }
  if (k != 0) {
    if (hx < 0x4b800000) {
      u = __fadd_rn(1.0f, x);
      int hu0 = __float_as_int(u);
      k = (hu0 >> 23) - 127;
      c = (k > 0) ? __fsub_rn(1.0f, __fsub_rn(u, x))
                  : __fsub_rn(x, __fsub_rn(u, 1.0f));
      c = __fdiv_rn(c, u);
      hu = hu0;
    } else {
      u = x; hu = __float_as_int(u); k = (hu >> 23) - 127; c = 0.f;
    }
    hu &= 0x007fffff;
    if (hu < 0x3504f7) { u = __int_as_float(hu | 0x3f800000); }
    else { k += 1; u = __int_as_float(hu | 0x3f000000); hu = (0x00800000 - hu) >> 2; }
    f = __fsub_rn(u, 1.0f);
  }
  float hfsq = __fmul_rn(__fmul_rn(0.5f, f), f);
  if (hu == 0) {
    if (f == 0.0f) {
      if (k == 0) return 0.0f;
      c = __fadd_rn(c, __fmul_rn((float)k, ln2_lo));
      return __fadd_rn(__fmul_rn((float)k, ln2_hi), c);
    }
    float R = __fmul_rn(hfsq, __fsub_rn(1.0f, __fmul_rn(0.66666668653f, f)));
    if (k == 0) return __fsub_rn(f, R);
    return __fsub_rn(__fmul_rn((float)k, ln2_hi),
           __fsub_rn(__fsub_rn(R, __fadd_rn(__fmul_rn((float)k, ln2_lo), c)), f));
  }
  float s = __fdiv_rn(f, __fadd_rn(2.0f, f));
  float z = __fmul_rn(s, s);
  float pz = __fadd_rn(Lp6, __fmul_rn(z, Lp7));
  pz = __fadd_rn(Lp5, __fmul_rn(z, pz));
  pz = __fadd_rn(Lp4, __fmul_rn(z, pz));
  pz = __fadd_rn(Lp3, __fmul_rn(z, pz));
  pz = __fadd_rn(Lp2, __fmul_rn(z, pz));
  pz = __fadd_rn(Lp1, __fmul_rn(z, pz));
  float R = __fmul_rn(z, pz);
  if (k == 0)
    return __fsub_rn(f, __fsub_rn(hfsq, __fmul_rn(s, __fadd_rn(hfsq, R))));
  return __fsub_rn(__fmul_rn((float)k, ln2_hi),
         __fsub_rn(__fsub_rn(hfsq, __fadd_rn(__fmul_rn(s, __fadd_rn(hfsq, R)),
                   __fadd_rn(__fmul_rn((float)k, ln2_lo), c))), f));
}

__device__ __forceinline__ float np_softplus(float x) {
  if (x == 0.0f) return __int_as_float(0x3F317218);
  if (x > 0.0f)  return __fadd_rn(x, log1pf_fd(expf_cr(-x)));
  return log1pf_fd(expf_cr(x));
}
// ===========================================================================

#define BM 128
#define BN 128
#define BK 32

// ---------------------------------------------------------------------------
// Kernel 1: dual GEMM — PURE ASCENDING TWO-ROUNDING CHAIN per output element.
// Dual 8x8 microtile (128x128 tile): halves LDS-read traffic per VALU op vs
// R14's 8x4 (the co-critical resource per the cycle model). All LDS access
// conflict-free by construction:
//  - xsT[k][m], write col m^((k>>2)<<3) (2-way), read (mg*8)^(kq<<3) (free)
//  - wds/wbs[k][n], write col n^((k>>2)<<2) (2-way), read n-quads {tx,16+tx}
//    -> cols 4*(tx^kq), 64+4*(tx^kq) (2-way free; R11's adjacent-quad read
//    was the 4-way conflict)
// Loads live only across one barrier (R13 lesson); no launch-bounds cap
// (R12 lesson). Per-element FP op sequence bit-identical to rounds 9-14.
// ---------------------------------------------------------------------------
__global__ __launch_bounds__(256) void gemm_np(
    const float* __restrict__ x,  const float* __restrict__ Wd,
    const float* __restrict__ bd, const float* __restrict__ Wb,
    const float* __restrict__ bb, const float* __restrict__ A_log,
    float* __restrict__ Aarr, float* __restrict__ Barr)
{
  __shared__ float xsT[BK][BM];     // 16 KB
  __shared__ float wds[BK][BN];     // 16 KB
  __shared__ float wbs[BK][BN];     // 16 KB

  const int tid = threadIdx.x;
  const int bn0 = blockIdx.x * BN;
  const int bm0 = blockIdx.y * BM;
  const int tx  = tid & 15;         // n-quads tx and 16+tx (cols tx*4, 64+tx*4)
  const int mg  = tid >> 4;         // m-octet: rows mg*8 .. +7

  const int sr8 = tid >> 3;         // 0..31
  const int sq  = tid & 7;          // 0..7 (k-quad staged)

  float accd[8][8], accb[8][8];
#pragma unroll
  for (int i = 0; i < 8; ++i)
#pragma unroll
    for (int j = 0; j < 8; ++j) { accd[i][j] = 0.f; accb[i][j] = 0.f; }

  for (int kt = 0; kt < DIN / BK; ++kt) {       // 16 k-tiles, ascending
    const int k0 = kt * BK;
    // loads (live only until the LDS writes below)
    float4 lx0 = *(const float4*)&x[(size_t)(bm0 +  0 + sr8) * DIN + k0 + sq * 4];
    float4 lx1 = *(const float4*)&x[(size_t)(bm0 + 32 + sr8) * DIN + k0 + sq * 4];
    float4 lx2 = *(const float4*)&x[(size_t)(bm0 + 64 + sr8) * DIN + k0 + sq * 4];
    float4 lx3 = *(const float4*)&x[(size_t)(bm0 + 96 + sr8) * DIN + k0 + sq * 4];
    float4 ld0 = *(const float4*)&Wd[(size_t)(bn0 +  0 + sr8) * DIN + k0 + sq * 4];
    float4 ld1 = *(const float4*)&Wd[(size_t)(bn0 + 32 + sr8) * DIN + k0 + sq * 4];
    float4 ld2 = *(const float4*)&Wd[(size_t)(bn0 + 64 + sr8) * DIN + k0 + sq * 4];
    float4 ld3 = *(const float4*)&Wd[(size_t)(bn0 + 96 + sr8) * DIN + k0 + sq * 4];
    float4 lb0 = *(const float4*)&Wb[(size_t)(bn0 +  0 + sr8) * DIN + k0 + sq * 4];
    float4 lb1 = *(const float4*)&Wb[(size_t)(bn0 + 32 + sr8) * DIN + k0 + sq * 4];
    float4 lb2 = *(const float4*)&Wb[(size_t)(bn0 + 64 + sr8) * DIN + k0 + sq * 4];
    float4 lb3 = *(const float4*)&Wb[(size_t)(bn0 + 96 + sr8) * DIN + k0 + sq * 4];
    __syncthreads();                             // prev compute done
    // x: write col = row ^ (sq<<3)
    {
      int r0 = sr8, r1 = 32 + sr8, r2 = 64 + sr8, r3 = 96 + sr8;
      int c0 = r0 ^ (sq << 3), c1 = r1 ^ (sq << 3);
      int c2 = r2 ^ (sq << 3), c3 = r3 ^ (sq << 3);
      xsT[sq*4+0][c0] = lx0.x; xsT[sq*4+1][c0] = lx0.y;
      xsT[sq*4+2][c0] = lx0.z; xsT[sq*4+3][c0] = lx0.w;
      xsT[sq*4+0][c1] = lx1.x; xsT[sq*4+1][c1] = lx1.y;
      xsT[sq*4+2][c1] = lx1.z; xsT[sq*4+3][c1] = lx1.w;
      xsT[sq*4+0][c2] = lx2.x; xsT[sq*4+1][c2] = lx2.y;
      xsT[sq*4+2][c2] = lx2.z; xsT[sq*4+3][c2] = lx2.w;
      xsT[sq*4+0][c3] = lx3.x; xsT[sq*4+1][c3] = lx3.y;
      xsT[sq*4+2][c3] = lx3.z; xsT[sq*4+3][c3] = lx3.w;
    }
    // W: write col = n ^ (sq<<2)
    {
      int n0 = sr8, n1 = 32 + sr8, n2 = 64 + sr8, n3 = 96 + sr8;
      int c0 = n0 ^ (sq << 2), c1 = n1 ^ (sq << 2);
      int c2 = n2 ^ (sq << 2), c3 = n3 ^ (sq << 2);
      wds[sq*4+0][c0] = ld0.x; wds[sq*4+1][c0] = ld0.y;
      wds[sq*4+2][c0] = ld0.z; wds[sq*4+3][c0] = ld0.w;
      wds[sq*4+0][c1] = ld1.x; wds[sq*4+1][c1] = ld1.y;
      wds[sq*4+2][c1] = ld1.z; wds[sq*4+3][c1] = ld1.w;
      wds[sq*4+0][c2] = ld2.x; wds[sq*4+1][c2] = ld2.y;
      wds[sq*4+2][c2] = ld2.z; wds[sq*4+3][c2] = ld2.w;
      wds[sq*4+0][c3] = ld3.x; wds[sq*4+1][c3] = ld3.y;
      wds[sq*4+2][c3] = ld3.z; wds[sq*4+3][c3] = ld3.w;
      wbs[sq*4+0][c0] = lb0.x; wbs[sq*4+1][c0] = lb0.y;
      wbs[sq*4+2][c0] = lb0.z; wbs[sq*4+3][c0] = lb0.w;
      wbs[sq*4+0][c1] = lb1.x; wbs[sq*4+1][c1] = lb1.y;
      wbs[sq*4+2][c1] = lb1.z; wbs[sq*4+3][c1] = lb1.w;
      wbs[sq*4+0][c2] = lb2.x; wbs[sq*4+1][c2] = lb2.y;
      wbs[sq*4+2][c2] = lb2.z; wbs[sq*4+3][c2] = lb2.w;
      wbs[sq*4+0][c3] = lb3.x; wbs[sq*4+1][c3] = lb3.y;
      wbs[sq*4+2][c3] = lb3.z; wbs[sq*4+3][c3] = lb3.w;
    }
    __syncthreads();

    // ---- compute on LDS tile kt ----
#pragma unroll 2
    for (int kq = 0; kq < BK / 4; ++kq) {        // 8 quads, ascending
      const int xc = (mg * 8) ^ (kq << 3);
      const int wc = 4 * (tx ^ kq);
#pragma unroll
      for (int t = 0; t < 4; ++t) {              // k within quad, ascending
        const int k = kq * 4 + t;
        float4 x0 = *(const float4*)&xsT[k][xc];
        float4 x1 = *(const float4*)&xsT[k][xc + 4];
        float4 d0 = *(const float4*)&wds[k][wc];
        float4 d1 = *(const float4*)&wds[k][wc + 64];
        float4 b0 = *(const float4*)&wbs[k][wc];
        float4 b1 = *(const float4*)&wbs[k][wc + 64];
        float xa[8]  = {x0.x, x0.y, x0.z, x0.w, x1.x, x1.y, x1.z, x1.w};
        float wd8[8] = {d0.x, d0.y, d0.z, d0.w, d1.x, d1.y, d1.z, d1.w};
        float wb8[8] = {b0.x, b0.y, b0.z, b0.w, b1.x, b1.y, b1.z, b1.w};
#pragma unroll
        for (int i = 0; i < 8; ++i) {
          const float xv = xa[i];
#pragma unroll
          for (int j = 0; j < 8; ++j) {
            accd[i][j] = __fadd_rn(accd[i][j], __fmul_rn(xv, wd8[j]));  // two-round
            accb[i][j] = __fadd_rn(accb[i][j], __fmul_rn(xv, wb8[j]));
          }
        }
      }
    }
  }

  // Epilogue (frozen numerics). j 0..3 -> n = bn0+tx*4+j; j 4..7 -> +64.
  const int na = bn0 + tx * 4;
  const int nb = na + 64;
  float bd8[8], bb8[8], eA8[8];
#pragma unroll
  for (int j = 0; j < 4; ++j) {
    bd8[j]   = bd[na + j];  bd8[4+j] = bd[nb + j];
    bb8[j]   = bb[na + j];  bb8[4+j] = bb[nb + j];
    eA8[j]   = np_expf(A_log[na + j]);
    eA8[4+j] = np_expf(A_log[nb + j]);
  }
#pragma unroll
  for (int i = 0; i < 8; ++i) {
    const int m = bm0 + mg * 8 + i;
    float av[8], bv[8];
#pragma unroll
    for (int j = 0; j < 8; ++j) {
      float z1b = __fadd_rn(accd[i][j], bd8[j]);
      float z2b = __fadd_rn(accb[i][j], bb8[j]);
      float delta = np_softplus(z1b);            // np.logaddexp(z1b, 0)
      float w  = __fmul_rn(delta, eA8[j]);
      av[j] = np_expf(-w);                       // np.exp: SIMD Pade
      bv[j] = __fmul_rn(delta, z2b);
    }
    float* Ap = &Aarr[(size_t)m * Dd];
    float* Bp = &Barr[(size_t)m * Dd];
    *(float4*)(Ap + na) = make_float4(av[0], av[1], av[2], av[3]);
    *(float4*)(Ap + nb) = make_float4(av[4], av[5], av[6], av[7]);
    *(float4*)(Bp + na) = make_float4(bv[0], bv[1], bv[2], bv[3]);
    *(float4*)(Bp + nb) = make_float4(bv[4], bv[5], bv[6], bv[7]);
  }
}

// ---------------------------------------------------------------------------
// Kernel 2: sequential spiking scan (frozen numerics), PF=32. Unchanged.
// ---------------------------------------------------------------------------
__global__ __launch_bounds__(64) void scan_np(
    const float* __restrict__ thr_arr, const float* __restrict__ h0,
    float* __restrict__ Aarr, float* __restrict__ Barr)
{
  const int bx = blockIdx.x;                       // 0..127
  const int b  = bx >> 4;                          // 0..7
  const int d  = ((bx & 15) << 6) + threadIdx.x;   // 0..1023

  const float thr = thr_arr[d];
  float h = h0[(size_t)b * Dd + d];

  float* Ap = Aarr + (size_t)b * Tt * Dd + d;
  float* Bp = Barr + (size_t)b * Tt * Dd + d;

  constexpr int PF = 32;
  float pa[PF], pb[PF];
#pragma unroll
  for (int k = 0; k < PF; ++k) {
    pa[k] = Ap[(size_t)k * Dd];
    pb[k] = Bp[(size_t)k * Dd];
  }

  for (int t0 = 0; t0 < Tt; t0 += PF) {
    const int t1 = t0 + PF;
    float na[PF], nb[PF];
    if (t1 < Tt) {
#pragma unroll
      for (int k = 0; k < PF; ++k) {
        na[k] = Ap[(size_t)(t1 + k) * Dd];
        nb[k] = Bp[(size_t)(t1 + k) * Dd];
      }
    }
#pragma unroll
    for (int k = 0; k < PF; ++k) {
      h = __fadd_rn(__fmul_rn(pa[k], h), pb[k]);
      const bool spike = __fsub_rn(h, thr) > 0.0f;
      h = spike ? 0.0f : h;
      Ap[(size_t)(t0 + k) * Dd] = h;
      Bp[(size_t)(t0 + k) * Dd] = spike ? 1.0f : 0.0f;
    }
    if (t1 < Tt) {
#pragma unroll
      for (int k = 0; k < PF; ++k) { pa[k] = na[k]; pb[k] = nb[k]; }
    }
  }
}

// ---------------------------------------------------------------------------
// Kernel 3: LayerNorm (fp64 stats). Unchanged.
// ---------------------------------------------------------------------------
__global__ __launch_bounds__(256) void ln_np(
    const float* __restrict__ gamma, const float* __restrict__ beta,
    float* __restrict__ H)
{
  const int row = blockIdx.x;
  const int tid = threadIdx.x;
  const size_t base = (size_t)row * Dd + (tid << 2);

  float4 v = *(const float4*)&H[base];

  __shared__ double red[4];
  __shared__ double red2[4];
  const int wave = tid >> 6, lane = tid & 63;

  double sum = (double)v.x + (double)v.y + (double)v.z + (double)v.w;
#pragma unroll
  for (int off = 32; off > 0; off >>= 1) sum += __shfl_down(sum, off);
  if (lane == 0) red[wave] = sum;
  __syncthreads();
  const float muf = (float)((red[0] + red[1] + red[2] + red[3]) * (1.0 / Dd));

  float dx0 = __fsub_rn(v.x, muf), dx1 = __fsub_rn(v.y, muf);
  float dx2 = __fsub_rn(v.z, muf), dx3 = __fsub_rn(v.w, muf);
  double sq = (double)dx0*dx0 + (double)dx1*dx1 + (double)dx2*dx2 + (double)dx3*dx3;
#pragma unroll
  for (int off = 32; off > 0; off >>= 1) sq += __shfl_down(sq, off);
  if (lane == 0) red2[wave] = sq;
  __syncthreads();
  const float varf = (float)((red2[0] + red2[1] + red2[2] + red2[3]) * (1.0 / Dd));
  const float invf = __fdiv_rn(1.0f, __fsqrt_rn(__fadd_rn(varf, 1e-5f)));

  const int n = tid << 2;
  float4 g  = *(const float4*)&gamma[n];
  float4 be = *(const float4*)&beta[n];
  float4 o;
  o.x = __fadd_rn(__fmul_rn(__fmul_rn(dx0, invf), g.x), be.x);
  o.y = __fadd_rn(__fmul_rn(__fmul_rn(dx1, invf), g.y), be.y);
  o.z = __fadd_rn(__fmul_rn(__fmul_rn(dx2, invf), g.z), be.z);
  o.w = __fadd_rn(__fmul_rn(__fmul_rn(dx3, invf), g.w), be.w);
  *(float4*)&H[base] = o;
}

// ---------------------------------------------------------------------------
extern "C" void kernel_launch(void* const* d_in, const int* in_sizes, int n_in,
                              void* d_out, int out_size, void* d_ws, size_t ws_size,
                              hipStream_t stream)
{
  const float* x     = (const float*)d_in[0];
  const float* Wd    = (const float*)d_in[1];
  const float* bd    = (const float*)d_in[2];
  const float* Wb    = (const float*)d_in[3];
  const float* bb    = (const float*)d_in[4];
  const float* A_log = (const float*)d_in[5];
  const float* thr   = (const float*)d_in[6];
  const float* gamma = (const float*)d_in[7];
  const float* beta  = (const float*)d_in[8];
  const float* h0    = (const float*)d_in[9];

  float* out  = (float*)d_out;
  float* Aarr = out;                  // A_step -> h_post -> LN out
  float* Barr = out + (size_t)BTD;    // b_step -> spikes

  dim3 g1(Dd / BN, (int)(BT / BM));   // (8, 128)
  gemm_np<<<g1, 256, 0, stream>>>(x, Wd, bd, Wb, bb, A_log, Aarr, Barr);
  scan_np<<<128, 64, 0, stream>>>(thr, h0, Aarr, Barr);
  ln_np<<<(int)BT, 256, 0, stream>>>(gamma, beta, Aarr);
}